// Round 1
// baseline (554.577 us; speedup 1.0000x reference)
//
#include <hip/hip_runtime.h>
#include <math.h>

#define NPIX 512
#define NT   256
#define NIMG 32
#define NBIN 258   // rings 0..256 valid, 257 = discard bin

// ---------------------------------------------------------------------------
// 512-point radix-2 Stockham FFT (DIT, autosort), 256 threads, one butterfly
// per thread per stage. src/dst ping-pong in LDS. Twiddle sign matches
// numpy/jax forward FFT (e^{-2πi kn/N}). Returns pointer to buffer holding
// the result (natural order).
// ---------------------------------------------------------------------------
__device__ __forceinline__ float2* fft512(float2* A, float2* B, int t) {
    float2* src = A;
    float2* dst = B;
#pragma unroll
    for (int s = 0; s < 9; ++s) {
        const int p = 1 << s;
        const int k = t & (p - 1);
        float2 a = src[t];
        float2 b = src[t + 256];
        float ang = -3.14159265358979323846f * (float)k / (float)p;
        float sw, cw;
        __sincosf(ang, &sw, &cw);
        float2 wb = make_float2(b.x * cw - b.y * sw, b.x * sw + b.y * cw);
        int di = (t << 1) - k;
        dst[di]     = make_float2(a.x + wb.x, a.y + wb.y);
        dst[di + p] = make_float2(a.x - wb.x, a.y - wb.y);
        __syncthreads();
        float2* tmp = src; src = dst; dst = tmp;
    }
    return src;  // after final swap, src holds the result
}

// ---------------------------------------------------------------------------
// Row pass: Z[b,y,:] = FFT(output[b,y,:] + i*target[b,y,:])
// ---------------------------------------------------------------------------
__global__ __launch_bounds__(NT) void fft_rows(const float* __restrict__ xr,
                                               const float* __restrict__ yr,
                                               float2* __restrict__ Z) {
    __shared__ float2 A[NPIX];
    __shared__ float2 B[NPIX];
    const int t = threadIdx.x;
    const size_t base = (size_t)blockIdx.x * NPIX;   // blockIdx = b*512 + y

    A[t]       = make_float2(xr[base + t],       yr[base + t]);
    A[t + 256] = make_float2(xr[base + t + 256], yr[base + t + 256]);
    __syncthreads();

    float2* res = fft512(A, B, t);

    Z[base + t]       = res[t];
    Z[base + t + 256] = res[t + 256];
}

// ---------------------------------------------------------------------------
// Column pass (in-place in Z): Z[b,:,x] = FFT(Z[b,:,x])
// Strided global access — round-1 simple version.
// ---------------------------------------------------------------------------
__global__ __launch_bounds__(NT) void fft_cols(float2* __restrict__ Z) {
    __shared__ float2 A[NPIX];
    __shared__ float2 B[NPIX];
    const int t = threadIdx.x;
    const int b = blockIdx.x >> 9;
    const int x = blockIdx.x & 511;
    const size_t base = (size_t)b * NPIX * NPIX + x;

    A[t]       = Z[base + (size_t)t * NPIX];
    A[t + 256] = Z[base + (size_t)(t + 256) * NPIX];
    __syncthreads();

    float2* res = fft512(A, B, t);

    Z[base + (size_t)t * NPIX]         = res[t];
    Z[base + (size_t)(t + 256) * NPIX] = res[t + 256];
}

// ---------------------------------------------------------------------------
// Ring reduction. 16 blocks per image, 16384 pixels per block.
// F1 = (Z(k)+conj(Z(-k)))/2 ; F2 = (Z(k)-conj(Z(-k)))/(2i) ; scale = 1/512^2
// sums[b][bin] = {sum a, sum b, sum c1, sum c2}
// ---------------------------------------------------------------------------
__global__ __launch_bounds__(NT) void rings(const float2* __restrict__ Z,
                                            float* __restrict__ sums) {
    __shared__ float bins[NBIN * 4];
    const int t = threadIdx.x;
    for (int i = t; i < NBIN * 4; i += NT) bins[i] = 0.0f;
    __syncthreads();

    const int b     = blockIdx.x >> 4;
    const int chunk = blockIdx.x & 15;
    const float2* Zb = Z + (size_t)b * NPIX * NPIX;
    const float scale = 1.0f / (float)(NPIX * NPIX);

#pragma unroll 4
    for (int i = 0; i < 64; ++i) {
        const int pix = chunk * 16384 + i * NT + t;
        const int ky = pix >> 9;
        const int kx = pix & 511;
        const int my = (NPIX - ky) & 511;
        const int mx = (NPIX - kx) & 511;

        float2 zk = Zb[pix];
        float2 zm = Zb[my * NPIX + mx];

        float f1r = 0.5f * (zk.x + zm.x) * scale;
        float f1i = 0.5f * (zk.y - zm.y) * scale;
        float f2r = 0.5f * (zk.y + zm.y) * scale;
        float f2i = 0.5f * (zm.x - zk.x) * scale;

        float av = f1r * f2r + f1i * f2i;
        float bv = f1i * f2r - f1r * f2i;
        float c1 = f1r * f1r + f1i * f1i;
        float c2 = f2r * f2r + f2i * f2i;

        float fx = (ky < 256) ? (float)ky : (float)(ky - NPIX);
        float fy = (kx < 256) ? (float)kx : (float)(kx - NPIX);
        int r = (int)rintf(sqrtf(fx * fx + fy * fy));
        if (r > 256) r = 257;

        atomicAdd(&bins[r * 4 + 0], av);
        atomicAdd(&bins[r * 4 + 1], bv);
        atomicAdd(&bins[r * 4 + 2], c1);
        atomicAdd(&bins[r * 4 + 3], c2);
    }
    __syncthreads();

    float* dst = sums + (size_t)b * NBIN * 4;
    for (int i = t; i < NBIN * 4; i += NT) atomicAdd(&dst[i], bins[i]);
}

// ---------------------------------------------------------------------------
// Finalize: mean over rings 0..256 and all 32 images of (1 - frc)^2
// ---------------------------------------------------------------------------
__global__ __launch_bounds__(NT) void finalize(const float* __restrict__ sums,
                                               float* __restrict__ out) {
    const int t = threadIdx.x;
    float acc = 0.0f;
    for (int i = t; i < 257 * NIMG; i += NT) {
        const int r = i % 257;
        const int b = i / 257;
        const float* s = sums + ((size_t)b * NBIN + r) * 4;
        float cr = s[0], ci = s[1], c1 = s[2], c2 = s[3];
        float num = sqrtf(cr * cr + ci * ci);
        float den = sqrtf(c1 * c2) + 1e-8f;
        float frc = num / den;
        float d = 1.0f - frc;
        acc += d * d;
    }
    // wave + block reduce
#pragma unroll
    for (int off = 32; off > 0; off >>= 1) acc += __shfl_down(acc, off);
    __shared__ float red[4];
    const int wave = t >> 6, lane = t & 63;
    if (lane == 0) red[wave] = acc;
    __syncthreads();
    if (t == 0) {
        float s = red[0] + red[1] + red[2] + red[3];
        out[0] = s / (257.0f * (float)NIMG);
    }
}

// ---------------------------------------------------------------------------
extern "C" void kernel_launch(void* const* d_in, const int* in_sizes, int n_in,
                              void* d_out, int out_size, void* d_ws, size_t ws_size,
                              hipStream_t stream) {
    const float* xr = (const float*)d_in[0];   // output: 32*1*512*512 f32
    const float* yr = (const float*)d_in[1];   // target: 32*1*512*512 f32

    float2* Z   = (float2*)d_ws;                                   // 64 MiB
    float* sums = (float*)((char*)d_ws +
                           (size_t)NIMG * NPIX * NPIX * sizeof(float2));

    hipMemsetAsync(sums, 0, (size_t)NIMG * NBIN * 4 * sizeof(float), stream);

    fft_rows<<<dim3(NIMG * NPIX), dim3(NT), 0, stream>>>(xr, yr, Z);
    fft_cols<<<dim3(NIMG * NPIX), dim3(NT), 0, stream>>>(Z);
    rings<<<dim3(NIMG * 16), dim3(NT), 0, stream>>>(Z, sums);
    finalize<<<dim3(1), dim3(NT), 0, stream>>>(sums, (float*)d_out);
}

// Round 2
// 323.692 us; speedup vs baseline: 1.7133x; 1.7133x over previous
//
#include <hip/hip_runtime.h>
#include <math.h>

#define NPIX  512
#define NIMG  32
#define NRING 257            // rings 0..256 kept; 257 = discard
#define PI_F  3.14159265358979323846f

__device__ __forceinline__ int bitrev9(int x) { return (int)(__brev((unsigned)x) >> 23); }

// ---------------------------------------------------------------------------
// Row pass: Z[b,y,:] = FFT512(output[b,y,:] + i*target[b,y,:]), natural order.
// Stockham ping-pong in LDS, twiddle table (1 sincos/thread).
// ---------------------------------------------------------------------------
__global__ __launch_bounds__(256) void fft_rows(const float* __restrict__ xr,
                                                const float* __restrict__ yr,
                                                float2* __restrict__ Z) {
    __shared__ float2 A[NPIX];
    __shared__ float2 B[NPIX];
    __shared__ float2 T[256];     // T[j] = e^{-2*pi*i*j/512}
    const int t = threadIdx.x;

    float sw, cw;
    __sincosf(-2.0f * PI_F * (float)t / 512.0f, &sw, &cw);
    T[t] = make_float2(cw, sw);

    const size_t base = (size_t)blockIdx.x * NPIX;
    float2 x2 = ((const float2*)(xr + base))[t];   // 8B coalesced
    float2 y2 = ((const float2*)(yr + base))[t];
    A[2 * t]     = make_float2(x2.x, y2.x);
    A[2 * t + 1] = make_float2(x2.y, y2.y);
    __syncthreads();

    float2* src = A;
    float2* dst = B;
#pragma unroll
    for (int s = 0; s < 9; ++s) {
        const int p = 1 << s;
        const int k = t & (p - 1);
        float2 a = src[t];
        float2 b = src[t + 256];
        float2 w = T[k << (8 - s)];        // e^{-i*pi*k/p}
        float2 wb = make_float2(b.x * w.x - b.y * w.y, b.x * w.y + b.y * w.x);
        int di = (t << 1) - k;
        dst[di]     = make_float2(a.x + wb.x, a.y + wb.y);
        dst[di + p] = make_float2(a.x - wb.x, a.y - wb.y);
        __syncthreads();
        float2* tmp = src; src = dst; dst = tmp;
    }

    // 16B coalesced store
    float4* Zo = (float4*)(Z + base);
    Zo[t] = make_float4(src[2 * t].x, src[2 * t].y, src[2 * t + 1].x, src[2 * t + 1].y);
}

// ---------------------------------------------------------------------------
// Fused column FFT + ring reduction.
// Each block: 8 columns closed under x -> (-x mod 512), 512 rows, in LDS.
//   block g=0   : cols {0,1,2,3, 256, 509,510,511}
//   block g>=1  : cols {4g..4g+3, 509-4g..512-4g}
// In-place DIF FFT along y (output bit-reversed: row i holds ky=bitrev9(i)).
// Then per-pixel unpack F1,F2 via conjugate pair (in-LDS) and bin a,c1,c2.
// ---------------------------------------------------------------------------
#define LDSW 9                // row stride in float2 (8 cols + 1 pad)

__global__ __launch_bounds__(512) void fft_cols_rings(const float2* __restrict__ Z,
                                                      float* __restrict__ sums) {
    __shared__ float2 D[NPIX * LDSW];    // 36,864 B
    __shared__ float2 T[256];            //  2,048 B
    __shared__ float  bins[258 * 3];     //  3,096 B
    const int t  = threadIdx.x;
    const int g  = blockIdx.x & 63;
    const int im = blockIdx.x >> 6;

    if (t < 256) {
        float sw, cw;
        __sincosf(-2.0f * PI_F * (float)t / 512.0f, &sw, &cw);
        T[t] = make_float2(cw, sw);
    }
    for (int i = t; i < 258 * 3; i += 512) bins[i] = 0.0f;

    const float2* Zb = Z + (size_t)im * NPIX * NPIX;

    // this thread's column (k = t&7) for load/FFT phases
    const int k = t & 7;
    int xcol;
    if (g == 0) xcol = (k < 4) ? k : ((k == 4) ? 256 : 504 + k);
    else        xcol = (k < 4) ? (4 * g + k) : (505 - 4 * g + k);

    // load: 8 iterations x 64 rows; lanes 0-3 / 4-7 hit 32B contiguous runs
#pragma unroll
    for (int u = 0; u < 8; ++u) {
        const int r = u * 64 + (t >> 3);
        D[r * LDSW + k] = Zb[(size_t)r * NPIX + xcol];
    }
    __syncthreads();

    // in-place DIF radix-2, 9 stages; 2048 butterflies/stage, 4 per thread
    for (int s = 0; s < 9; ++s) {
        const int p = 256 >> s;
#pragma unroll
        for (int u = 0; u < 4; ++u) {
            const int j  = u * 64 + (t >> 3);        // butterfly 0..255
            const int jl = j & (p - 1);
            const int i  = ((j & ~(p - 1)) << 1) + jl;
            float2 a = D[i * LDSW + k];
            float2 b = D[(i + p) * LDSW + k];
            float2 w = T[jl << s];
            D[i * LDSW + k] = make_float2(a.x + b.x, a.y + b.y);
            float2 amb = make_float2(a.x - b.x, a.y - b.y);
            D[(i + p) * LDSW + k] = make_float2(amb.x * w.x - amb.y * w.y,
                                                amb.x * w.y + amb.y * w.x);
        }
        __syncthreads();
    }

    // ring accumulation: iterate u = local column (uniform), row = t
    const int ky    = bitrev9(t);
    const int ipair = bitrev9((512 - ky) & 511);
    const float fxv = (ky < 256) ? (float)ky : (float)(ky - 512);
    const float scale = 1.0f / (512.0f * 512.0f);

    for (int u = 0; u < 8; ++u) {
        int xk, mu;
        if (g == 0) { xk = (u < 4) ? u : ((u == 4) ? 256 : 504 + u); mu = (8 - u) & 7; }
        else        { xk = (u < 4) ? (4 * g + u) : (505 - 4 * g + u); mu = 7 - u; }

        float2 zk = D[t * LDSW + u];
        float2 zm = D[ipair * LDSW + mu];

        float f1r = 0.5f * (zk.x + zm.x) * scale;
        float f1i = 0.5f * (zk.y - zm.y) * scale;
        float f2r = 0.5f * (zk.y + zm.y) * scale;
        float f2i = 0.5f * (zm.x - zk.x) * scale;

        float av = f1r * f2r + f1i * f2i;
        float c1 = f1r * f1r + f1i * f1i;
        float c2 = f2r * f2r + f2i * f2i;

        float fyv = (xk < 256) ? (float)xk : (float)(xk - 512);
        int r = (int)rintf(sqrtf(fxv * fxv + fyv * fyv));
        if (r > 256) r = 257;

        atomicAdd(&bins[r * 3 + 0], av);
        atomicAdd(&bins[r * 3 + 1], c1);
        atomicAdd(&bins[r * 3 + 2], c2);
    }
    __syncthreads();

    float* dstp = sums + (size_t)im * NRING * 3;
    for (int i = t; i < NRING * 3; i += 512) atomicAdd(&dstp[i], bins[i]);
}

// ---------------------------------------------------------------------------
// Finalize: mean over rings 0..256, all 32 images, of (1 - frc)^2.
// C_i term dropped (exactly antisymmetric under k->-k; ring sums are 0).
// ---------------------------------------------------------------------------
__global__ __launch_bounds__(256) void finalize(const float* __restrict__ sums,
                                                float* __restrict__ out) {
    const int t = threadIdx.x;
    float acc = 0.0f;
    for (int i = t; i < NRING * NIMG; i += 256) {
        const int r = i % NRING;
        const int b = i / NRING;
        const float* s = sums + ((size_t)b * NRING + r) * 3;
        float cr = s[0], c1 = s[1], c2 = s[2];
        float frc = fabsf(cr) / (sqrtf(c1 * c2) + 1e-8f);
        float d = 1.0f - frc;
        acc += d * d;
    }
#pragma unroll
    for (int off = 32; off > 0; off >>= 1) acc += __shfl_down(acc, off);
    __shared__ float red[4];
    const int wave = t >> 6, lane = t & 63;
    if (lane == 0) red[wave] = acc;
    __syncthreads();
    if (t == 0) {
        out[0] = (red[0] + red[1] + red[2] + red[3]) / (float)(NRING * NIMG);
    }
}

// ---------------------------------------------------------------------------
extern "C" void kernel_launch(void* const* d_in, const int* in_sizes, int n_in,
                              void* d_out, int out_size, void* d_ws, size_t ws_size,
                              hipStream_t stream) {
    const float* xr = (const float*)d_in[0];   // output: 32x1x512x512 f32
    const float* yr = (const float*)d_in[1];   // target: 32x1x512x512 f32

    float2* Z   = (float2*)d_ws;               // 67,108,864 B
    float*  sums = (float*)((char*)d_ws + (size_t)NIMG * NPIX * NPIX * sizeof(float2));

    hipMemsetAsync(sums, 0, (size_t)NIMG * NRING * 3 * sizeof(float), stream);

    fft_rows<<<dim3(NIMG * NPIX), dim3(256), 0, stream>>>(xr, yr, Z);
    fft_cols_rings<<<dim3(NIMG * 64), dim3(512), 0, stream>>>(Z, sums);
    finalize<<<dim3(1), dim3(256), 0, stream>>>(sums, (float*)d_out);
}

// Round 3
// 245.245 us; speedup vs baseline: 2.2613x; 1.3199x over previous
//
#include <hip/hip_runtime.h>
#include <math.h>

#define NPIX  512
#define NIMG  32
#define NRING 257            // rings 0..256 kept; bin 257 = discard
#define PI_F  3.14159265358979323846f
#define RSTR  576            // padded row stride in float2 (512 + 512/8)
#define TSTR  288            // padded twiddle size

__device__ __forceinline__ int bitrev9(int x) { return (int)(__brev((unsigned)x) >> 23); }
// LDS anti-conflict swizzle: insert one float2 pad every 8 positions.
// Breaks all power-of-2 stride patterns of the FFT stages.
__device__ __forceinline__ int SW(int pos) { return pos + (pos >> 3); }

// ---------------------------------------------------------------------------
// Row pass, 8 rows per block, in-place DIF (output bit-reversed in LDS),
// bit-reversal undone at the transposed global write.
// Zt[kx][y] layout: column kernel then reads columns contiguously.
// ---------------------------------------------------------------------------
__global__ __launch_bounds__(512) void fft_rows_T(const float* __restrict__ xr,
                                                  const float* __restrict__ yr,
                                                  float2* __restrict__ Zt) {
    __shared__ float2 D[8 * RSTR];     // 36,864 B
    __shared__ float2 T[TSTR];         //  2,304 B
    const int t   = threadIdx.x;
    const int im  = blockIdx.x >> 6;
    const int grp = blockIdx.x & 63;   // rows grp*8 .. grp*8+7

    if (t < 256) {
        float sw, cw;
        __sincosf(-2.0f * PI_F * (float)t / 512.0f, &sw, &cw);
        T[SW(t)] = make_float2(cw, sw);
    }

    const size_t base = ((size_t)im * 512 + (size_t)grp * 8) * 512;
    const float4* x4 = (const float4*)(xr + base);
    const float4* y4 = (const float4*)(yr + base);
#pragma unroll
    for (int i = 0; i < 2; ++i) {
        const int idx = i * 512 + t;        // 0..1023 float4 (8 rows x 128)
        float4 a = x4[idx];
        float4 b = y4[idx];
        const int p0  = idx * 4;            // float2 position, row-major 8x512
        const int row = p0 >> 9;
        const int pos = p0 & 511;
        float2* Dst = D + row * RSTR + SW(pos);   // SW(pos+e)=SW(pos)+e, e<4
        Dst[0] = make_float2(a.x, b.x);
        Dst[1] = make_float2(a.y, b.y);
        Dst[2] = make_float2(a.z, b.z);
        Dst[3] = make_float2(a.w, b.w);
    }
    __syncthreads();

    for (int s = 0; s < 9; ++s) {
        const int p = 256 >> s;
#pragma unroll
        for (int u = 0; u < 4; ++u) {
            const int q   = u * 512 + t;        // 0..2047 butterflies
            const int row = q >> 8;
            const int j   = q & 255;
            const int jl  = j & (p - 1);
            const int i0  = ((j & ~(p - 1)) << 1) + jl;
            float2* R = D + row * RSTR;
            float2 a = R[SW(i0)];
            float2 b = R[SW(i0 + p)];
            float2 w = T[SW(jl << s)];
            R[SW(i0)] = make_float2(a.x + b.x, a.y + b.y);
            float2 m = make_float2(a.x - b.x, a.y - b.y);
            R[SW(i0 + p)] = make_float2(m.x * w.x - m.y * w.y,
                                        m.x * w.y + m.y * w.x);
        }
        __syncthreads();
    }

    // LDS position t holds frequency kx = bitrev9(t) of each row.
    // Write Zt[kx][grp*8 .. grp*8+7]: 64 B contiguous per thread (full line).
    const int kx = bitrev9(t);
    float4* o4 = (float4*)(Zt + (size_t)im * 512 * 512 + (size_t)kx * 512 + (size_t)grp * 8);
    const int sp = SW(t);
#pragma unroll
    for (int y = 0; y < 4; ++y) {
        float2 e0 = D[(2 * y)     * RSTR + sp];
        float2 e1 = D[(2 * y + 1) * RSTR + sp];
        o4[y] = make_float4(e0.x, e0.y, e1.x, e1.y);
    }
}

// ---------------------------------------------------------------------------
// Column FFT (contiguous loads from Zt) + fused ring reduction.
// Block g owns 8 columns closed under x -> -x mod 512:
//   g=0 : {0,1,2,3, 256, 509,510,511}   (mirror map u -> (8-u)&7)
//   g>0 : {4g..4g+3, 509-4g..512-4g}    (mirror map u -> 7-u)
// Mirror columns share the ring index -> pair-merged LDS atomics.
// ---------------------------------------------------------------------------
__global__ __launch_bounds__(512) void fft_cols_rings(const float2* __restrict__ Zt,
                                                      float* __restrict__ sums) {
    __shared__ float2 E[8 * RSTR];     // 36,864 B
    __shared__ float2 T[TSTR];         //  2,304 B
    __shared__ float  bins[258 * 3];   //  3,096 B
    const int t  = threadIdx.x;
    const int im = blockIdx.x >> 6;
    const int g  = blockIdx.x & 63;

    if (t < 256) {
        float sw, cw;
        __sincosf(-2.0f * PI_F * (float)t / 512.0f, &sw, &cw);
        T[SW(t)] = make_float2(cw, sw);
    }
    for (int i = t; i < 258 * 3; i += 512) bins[i] = 0.0f;

    const float2* Zb = Zt + (size_t)im * 512 * 512;

    int cols[8];
    if (g == 0) {
        cols[0]=0; cols[1]=1; cols[2]=2; cols[3]=3;
        cols[4]=256; cols[5]=509; cols[6]=510; cols[7]=511;
    } else {
#pragma unroll
        for (int u = 0; u < 4; ++u) { cols[u] = 4*g + u; cols[4+u] = 509 - 4*g + u; }
    }

    // contiguous 4 KB load per column
#pragma unroll
    for (int u = 0; u < 8; ++u)
        E[u * RSTR + SW(t)] = Zb[(size_t)cols[u] * 512 + t];
    __syncthreads();

    for (int s = 0; s < 9; ++s) {
        const int p = 256 >> s;
#pragma unroll
        for (int u = 0; u < 4; ++u) {
            const int q  = u * 512 + t;
            const int c  = q >> 8;
            const int j  = q & 255;
            const int jl = j & (p - 1);
            const int i0 = ((j & ~(p - 1)) << 1) + jl;
            float2* R = E + c * RSTR;
            float2 a = R[SW(i0)];
            float2 b = R[SW(i0 + p)];
            float2 w = T[SW(jl << s)];
            R[SW(i0)] = make_float2(a.x + b.x, a.y + b.y);
            float2 m = make_float2(a.x - b.x, a.y - b.y);
            R[SW(i0 + p)] = make_float2(m.x * w.x - m.y * w.y,
                                        m.x * w.y + m.y * w.x);
        }
        __syncthreads();
    }

    // ring accumulation; LDS row position t holds ky = bitrev9(t)
    const int   ky    = bitrev9(t);
    const int   ip    = bitrev9((512 - ky) & 511);   // LDS pos of row -ky
    const float fxv   = (ky < 256) ? (float)ky : (float)(ky - 512);
    const float fx2   = fxv * fxv;
    const float scale = 1.0f / (512.0f * 512.0f);
    const int   spt   = SW(t);
    const int   spp   = SW(ip);

    // one pixel at (ky, col c); conjugate partner at (-ky, mirror col cm)
    auto pixel = [&](int c, int cm, float& av, float& c1, float& c2) {
        float2 zk = E[c  * RSTR + spt];
        float2 zm = E[cm * RSTR + spp];
        float f1r = 0.5f * (zk.x + zm.x) * scale;
        float f1i = 0.5f * (zk.y - zm.y) * scale;
        float f2r = 0.5f * (zk.y + zm.y) * scale;
        float f2i = 0.5f * (zm.x - zk.x) * scale;
        av = f1r * f2r + f1i * f2i;
        c1 = f1r * f1r + f1i * f1i;
        c2 = f2r * f2r + f2i * f2i;
    };
    auto deposit = [&](float fy, float av, float c1, float c2) {
        int r = (int)rintf(sqrtf(fx2 + fy * fy));
        if (r > 256) r = 257;
        atomicAdd(&bins[r * 3 + 0], av);
        atomicAdd(&bins[r * 3 + 1], c1);
        atomicAdd(&bins[r * 3 + 2], c2);
    };

    if (g == 0) {
        float av, c1, c2;
        pixel(0, 0, av, c1, c2);  deposit(0.0f,   av, c1, c2);   // col 0 (self)
        pixel(4, 4, av, c1, c2);  deposit(256.0f, av, c1, c2);   // col 256 (self)
#pragma unroll
        for (int u = 1; u < 4; ++u) {                            // pairs (u, 512-u)
            float a1, b1, d1, a2, b2, d2;
            pixel(u,     8 - u, a1, b1, d1);
            pixel(8 - u, u,     a2, b2, d2);
            deposit((float)u, a1 + a2, b1 + b2, d1 + d2);
        }
    } else {
#pragma unroll
        for (int u = 0; u < 4; ++u) {                            // pairs (4g+u, 512-(4g+u))
            float a1, b1, d1, a2, b2, d2;
            pixel(u,     7 - u, a1, b1, d1);
            pixel(7 - u, u,     a2, b2, d2);
            deposit((float)(4 * g + u), a1 + a2, b1 + b2, d1 + d2);
        }
    }
    __syncthreads();

    float* dstp = sums + (size_t)im * NRING * 3;
    for (int i = t; i < NRING * 3; i += 512) atomicAdd(&dstp[i], bins[i]);
}

// ---------------------------------------------------------------------------
// Finalize: mean over rings 0..256, all 32 images, of (1 - frc)^2.
// C_i ring sums are exactly 0 by k -> -k antisymmetry; dropped.
// ---------------------------------------------------------------------------
__global__ __launch_bounds__(256) void finalize(const float* __restrict__ sums,
                                                float* __restrict__ out) {
    const int t = threadIdx.x;
    float acc = 0.0f;
    for (int i = t; i < NRING * NIMG; i += 256) {
        const int r = i % NRING;
        const int b = i / NRING;
        const float* s = sums + ((size_t)b * NRING + r) * 3;
        float cr = s[0], c1 = s[1], c2 = s[2];
        float frc = fabsf(cr) / (sqrtf(c1 * c2) + 1e-8f);
        float d = 1.0f - frc;
        acc += d * d;
    }
#pragma unroll
    for (int off = 32; off > 0; off >>= 1) acc += __shfl_down(acc, off);
    __shared__ float red[4];
    const int wave = t >> 6, lane = t & 63;
    if (lane == 0) red[wave] = acc;
    __syncthreads();
    if (t == 0) {
        out[0] = (red[0] + red[1] + red[2] + red[3]) / (float)(NRING * NIMG);
    }
}

// ---------------------------------------------------------------------------
extern "C" void kernel_launch(void* const* d_in, const int* in_sizes, int n_in,
                              void* d_out, int out_size, void* d_ws, size_t ws_size,
                              hipStream_t stream) {
    const float* xr = (const float*)d_in[0];   // output: 32x1x512x512 f32
    const float* yr = (const float*)d_in[1];   // target: 32x1x512x512 f32

    float2* Zt  = (float2*)d_ws;               // 67,108,864 B
    float* sums = (float*)((char*)d_ws + (size_t)NIMG * NPIX * NPIX * sizeof(float2));

    hipMemsetAsync(sums, 0, (size_t)NIMG * NRING * 3 * sizeof(float), stream);

    fft_rows_T    <<<dim3(NIMG * 64), dim3(512), 0, stream>>>(xr, yr, Zt);
    fft_cols_rings<<<dim3(NIMG * 64), dim3(512), 0, stream>>>(Zt, sums);
    finalize      <<<dim3(1), dim3(256), 0, stream>>>(sums, (float*)d_out);
}

// Round 4
// 216.766 us; speedup vs baseline: 2.5584x; 1.1314x over previous
//
#include <hip/hip_runtime.h>
#include <math.h>

#define NIMG  32
#define NRING 257            // rings 0..256 kept
#define NB3   771            // 257*3 floats per (img,slice)
#define PI_F  3.14159265358979323846f

// ---------------------------------------------------------------------------
// complex helpers
// ---------------------------------------------------------------------------
__device__ __forceinline__ float2 cadd(float2 a, float2 b){ return make_float2(a.x+b.x, a.y+b.y); }
__device__ __forceinline__ float2 csub(float2 a, float2 b){ return make_float2(a.x-b.x, a.y-b.y); }
__device__ __forceinline__ float2 cmul(float2 a, float2 b){ return make_float2(a.x*b.x - a.y*b.y, a.x*b.y + a.y*b.x); }
__device__ __forceinline__ float2 cmul_mi(float2 a){ return make_float2(a.y, -a.x); }   // * (-i)

// twiddle table lookup, table stored at swizzled position m + m/8
__device__ __forceinline__ float2 tw(const float2* T, int m){ return T[m + (m >> 3)]; }

// 8-point DFT (DIF, natural-order outputs), e^{-2pi i/8} convention
__device__ __forceinline__ void dft8(float2* x) {
    const float c = 0.70710678118654752f;
    float2 u0 = cadd(x[0], x[4]), u1 = cadd(x[1], x[5]);
    float2 u2 = cadd(x[2], x[6]), u3 = cadd(x[3], x[7]);
    float2 v0 = csub(x[0], x[4]);
    float2 d1 = csub(x[1], x[5]);
    float2 v1 = make_float2(c*(d1.x + d1.y), c*(d1.y - d1.x));      // * c(1-i)
    float2 d2 = csub(x[2], x[6]);
    float2 v2 = make_float2(d2.y, -d2.x);                           // * -i
    float2 d3 = csub(x[3], x[7]);
    float2 v3 = make_float2(-c*(d3.x - d3.y), -c*(d3.x + d3.y));    // * -c(1+i)
    float2 e0 = cadd(u0,u2), e1 = cadd(u1,u3);
    float2 f0 = csub(u0,u2), f1 = cmul_mi(csub(u1,u3));
    float2 g0 = cadd(v0,v2), g1 = cadd(v1,v3);
    float2 h0 = csub(v0,v2), h1 = cmul_mi(csub(v1,v3));
    x[0] = cadd(e0,e1); x[4] = csub(e0,e1);
    x[2] = cadd(f0,f1); x[6] = csub(f0,f1);
    x[1] = cadd(g0,g1); x[5] = csub(g0,g1);
    x[3] = cadd(h0,h1); x[7] = csub(h0,h1);
}

// ---------------------------------------------------------------------------
// Per-wave 512-pt radix-8 DIF FFT. Thread J of the wave enters with
// X[q] = x[J + 64q] and exits with X[k] = F(64k + r), r = 8*(J&7) + (J>>3).
// Sw = this wave's 576-float2 LDS scratch (pos + pos/8 swizzle).
// Two block barriers inside (stage boundaries).
// ---------------------------------------------------------------------------
__device__ __forceinline__ void wave_fft512(float2* X, float2* Sw,
                                            const float2* T, int J) {
    // stage 1: DFT8 + W512^{Jk}, write pos J + 64k -> swizzled jj + 72k
    dft8(X);
#pragma unroll
    for (int k = 1; k < 8; ++k) X[k] = cmul(X[k], tw(T, J * k));
    const int jj = J + (J >> 3);
#pragma unroll
    for (int k = 0; k < 8; ++k) Sw[jj + 72 * k] = X[k];
    __syncthreads();

    // stage 2: read pos 64B + j2 + 8q -> bb + 9q ; DFT8 + W64^{j2 k}; same pos back
    const int j2 = J & 7;
    const int bb = 72 * (J >> 3) + j2;
#pragma unroll
    for (int q = 0; q < 8; ++q) X[q] = Sw[bb + 9 * q];
    dft8(X);
#pragma unroll
    for (int k = 1; k < 8; ++k) X[k] = cmul(X[k], tw(T, 8 * j2 * k));
#pragma unroll
    for (int k = 0; k < 8; ++k) Sw[bb + 9 * k] = X[k];
    __syncthreads();

    // stage 3: read pos 8J + q -> contiguous 9J + q ; DFT8 (no twiddle)
#pragma unroll
    for (int q = 0; q < 8; ++q) X[q] = Sw[9 * J + q];
    dft8(X);
}

// ---------------------------------------------------------------------------
// Row pass: wave w handles image row y = grp*8 + w.
// Output transposed: Zt[kx][y], natural kx order, full-line coalesced stores.
// ---------------------------------------------------------------------------
__global__ __launch_bounds__(512) void fft_rows_T(const float* __restrict__ xr,
                                                  const float* __restrict__ yr,
                                                  float2* __restrict__ Zt) {
    __shared__ float2 S[8 * 576];   // 36,864 B (FFT scratch, then kx-major transpose buf)
    __shared__ float2 T[576];       //  4,608 B
    const int t = threadIdx.x, w = t >> 6, J = t & 63;
    const int im = blockIdx.x >> 6, grp = blockIdx.x & 63;

    {   // T[m] = e^{-2pi i m/512}, swizzled
        float sw, cw;
        __sincosf(-2.0f * PI_F * (float)t / 512.0f, &sw, &cw);
        T[t + (t >> 3)] = make_float2(cw, sw);
    }

    const size_t rb = ((size_t)(im * 512 + grp * 8 + w)) << 9;
    float2 X[8];
#pragma unroll
    for (int q = 0; q < 8; ++q)
        X[q] = make_float2(xr[rb + J + 64 * q], yr[rb + J + 64 * q]);
    __syncthreads();                          // T ready

    wave_fft512(X, S + w * 576, T, J);
    __syncthreads();                          // all stage-3 reads done before W clobbers S

    // transpose into S as W[kx][row]: pos = 8*F + w, F = 64k + r -> swizzled 576k + 9r + w
    const int r = ((J & 7) << 3) | (J >> 3);
#pragma unroll
    for (int k = 0; k < 8; ++k) S[576 * k + 9 * r + w] = X[k];
    __syncthreads();

    // thread t writes Zt[kx=t][grp*8 .. grp*8+8): 64 B contiguous
    float4* o4 = (float4*)(Zt + ((size_t)im << 18) + ((size_t)t << 9) + (grp << 3));
#pragma unroll
    for (int i = 0; i < 4; ++i) {
        float2 e0 = S[9 * t + 2 * i];
        float2 e1 = S[9 * t + 2 * i + 1];
        o4[i] = make_float4(e0.x, e0.y, e1.x, e1.y);
    }
}

// ---------------------------------------------------------------------------
// Column pass + fused rings. Wave w handles column kx = cols[w] (a contiguous
// row of Zt). Block's 8 columns are closed under kx -> -kx:
//   g=0 : {0,1,2,3, 256, 509,510,511}  (mirror u -> (8-u)&7)
//   g>0 : {4g..4g+3, 509-4g..512-4g}   (mirror u -> 7-u)
// ---------------------------------------------------------------------------
__global__ __launch_bounds__(512) void fft_cols_rings(const float2* __restrict__ Zt,
                                                      float* __restrict__ sums) {
    __shared__ float2 S[8 * 576];
    __shared__ float2 T[576];
    __shared__ float  bins[258 * 3];
    const int t = threadIdx.x, w = t >> 6, J = t & 63;
    const int im = blockIdx.x >> 6, g = blockIdx.x & 63;

    {
        float sw, cw;
        __sincosf(-2.0f * PI_F * (float)t / 512.0f, &sw, &cw);
        T[t + (t >> 3)] = make_float2(cw, sw);
    }
    for (int i = t; i < 258 * 3; i += 512) bins[i] = 0.0f;

    int kxw;
    if (g == 0) kxw = (w < 4) ? w : ((w == 4) ? 256 : 504 + w);
    else        kxw = (w < 4) ? (4 * g + w) : (505 - 4 * g + w);

    const float2* rowp = Zt + ((size_t)im << 18) + ((size_t)kxw << 9);
    float2 X[8];
#pragma unroll
    for (int q = 0; q < 8; ++q) X[q] = rowp[J + 64 * q];
    __syncthreads();

    wave_fft512(X, S + w * 576, T, J);

    // un-digit-reverse into own wave row, natural ky index (same-wave region:
    // program order + same-array ensures stage-3 reads precede these writes)
    const int r = ((J & 7) << 3) | (J >> 3);
#pragma unroll
    for (int k = 0; k < 8; ++k) S[w * 576 + 64 * k + r] = X[k];
    __syncthreads();

    // ring phase: thread t = ky
    const int   ky  = t;
    const int   kyp = (512 - t) & 511;
    const float fxv = (ky < 256) ? (float)ky : (float)(ky - 512);
    const float fx2 = fxv * fxv;
    const float scale = 1.0f / (512.0f * 512.0f);

    auto pixel = [&](int u, int mu, float& av, float& c1, float& c2) {
        float2 zk = S[u  * 576 + ky];
        float2 zm = S[mu * 576 + kyp];
        float f1r = 0.5f * (zk.x + zm.x) * scale;
        float f1i = 0.5f * (zk.y - zm.y) * scale;
        float f2r = 0.5f * (zk.y + zm.y) * scale;
        float f2i = 0.5f * (zm.x - zk.x) * scale;
        av = f1r * f2r + f1i * f2i;
        c1 = f1r * f1r + f1i * f1i;
        c2 = f2r * f2r + f2i * f2i;
    };
    auto deposit = [&](float fy, float av, float c1, float c2) {
        int rr = (int)rintf(sqrtf(fx2 + fy * fy));
        if (rr > 256) rr = 257;
        atomicAdd(&bins[rr * 3 + 0], av);
        atomicAdd(&bins[rr * 3 + 1], c1);
        atomicAdd(&bins[rr * 3 + 2], c2);
    };

    if (g == 0) {
        float av, c1, c2;
        pixel(0, 0, av, c1, c2);  deposit(0.0f,   av, c1, c2);
        pixel(4, 4, av, c1, c2);  deposit(256.0f, av, c1, c2);
#pragma unroll
        for (int u = 1; u < 4; ++u) {
            float a1, b1, d1v, a2, b2, d2v;
            pixel(u,     8 - u, a1, b1, d1v);
            pixel(8 - u, u,     a2, b2, d2v);
            deposit((float)u, a1 + a2, b1 + b2, d1v + d2v);
        }
    } else {
#pragma unroll
        for (int u = 0; u < 4; ++u) {
            float a1, b1, d1v, a2, b2, d2v;
            pixel(u,     7 - u, a1, b1, d1v);
            pixel(7 - u, u,     a2, b2, d2v);
            deposit((float)(4 * g + u), a1 + a2, b1 + b2, d1v + d2v);
        }
    }
    __syncthreads();

    // flush, sliced 8 ways to cut global-atomic contention (8 blocks/slice)
    float* dstp = sums + (size_t)(im * 8 + (g & 7)) * NB3;
    for (int i = t; i < NB3; i += 512) atomicAdd(&dstp[i], bins[i]);
}

// ---------------------------------------------------------------------------
// Finalize: block b = image; sum 8 slices per ring, mean of (1-frc)^2.
// C_i term dropped: ring sums are exactly 0 by k -> -k antisymmetry.
// ---------------------------------------------------------------------------
__global__ __launch_bounds__(256) void finalize(const float* __restrict__ sums,
                                                float* __restrict__ out) {
    const int b = blockIdx.x, t = threadIdx.x;
    float acc = 0.0f;
    for (int r = t; r < NRING; r += 256) {
        float cr = 0.f, c1 = 0.f, c2 = 0.f;
#pragma unroll
        for (int s = 0; s < 8; ++s) {
            const float* p = sums + (size_t)(b * 8 + s) * NB3 + r * 3;
            cr += p[0]; c1 += p[1]; c2 += p[2];
        }
        float frc = fabsf(cr) / (sqrtf(c1 * c2) + 1e-8f);
        float d = 1.0f - frc;
        acc += d * d;
    }
#pragma unroll
    for (int off = 32; off > 0; off >>= 1) acc += __shfl_down(acc, off);
    __shared__ float red[4];
    if ((t & 63) == 0) red[t >> 6] = acc;
    __syncthreads();
    if (t == 0)
        atomicAdd(out, (red[0] + red[1] + red[2] + red[3]) *
                       (1.0f / (NRING * (float)NIMG)));
}

// ---------------------------------------------------------------------------
extern "C" void kernel_launch(void* const* d_in, const int* in_sizes, int n_in,
                              void* d_out, int out_size, void* d_ws, size_t ws_size,
                              hipStream_t stream) {
    const float* xr = (const float*)d_in[0];   // output: 32x1x512x512 f32
    const float* yr = (const float*)d_in[1];   // target: 32x1x512x512 f32

    float2* Zt  = (float2*)d_ws;                                   // 64 MiB
    float*  sums = (float*)((char*)d_ws + (((size_t)NIMG << 18) * sizeof(float2)));

    hipMemsetAsync(sums, 0, (size_t)NIMG * 8 * NB3 * sizeof(float), stream);
    hipMemsetAsync(d_out, 0, sizeof(float), stream);

    fft_rows_T    <<<dim3(NIMG * 64), dim3(512), 0, stream>>>(xr, yr, Zt);
    fft_cols_rings<<<dim3(NIMG * 64), dim3(512), 0, stream>>>(Zt, sums);
    finalize      <<<dim3(NIMG), dim3(256), 0, stream>>>(sums, (float*)d_out);
}